// Round 8
// baseline (277.734 us; speedup 1.0000x reference)
//
#include <hip/hip_runtime.h>
#include <cstdint>

// GCN via radix partition (bucket = node>>9), packed u32 edge records.
// part1a: edge histograms (block-local -> rawD/rawS, global tot via atomics)
//         + gcnt + wprep tail blocks (W1 transpose, Z8 zero row).
// pscanB: scan tot -> bsD/bsS, seed global bucket cursors curD/curS.
// part1c v4: single pass, both tables LDS-staged; block run-space claimed
//            via ONE global atomicAdd per bucket (pscanA deleted).
// part2d: norm fused + degree histogram for balance-sort.
// dperm: self-scanning counting-sort scatter (dscan folded in).
// gemm1 v4: 2 tiles/block, all X loads in flight across Wt staging.
// layer1 v7: degree-DESC perm, octet owns a dst, uint4 gathers, persistent
//            grid-stride, 2048 blocks.

#define DD 128
#define PB 512    // partition pass-1 blocks
#define GB 384    // poolgemm split-K blocks
#define KC 32     // poolgemm K-chunk
#define CHK 3200  // max edges per part1c block

typedef __attribute__((ext_vector_type(8))) short bf16x8;
typedef __attribute__((ext_vector_type(4))) float f32x4;
typedef __attribute__((ext_vector_type(2))) float f32x2;

__device__ __forceinline__ unsigned short f2bf(float f) {
  union { float f; unsigned u; } v; v.f = f;
  unsigned r = (v.u + 0x7fff + ((v.u >> 16) & 1)) >> 16;   // round-nearest-even
  return (unsigned short)r;
}
__device__ __forceinline__ unsigned cvt_pk_bf16(float lo, float hi) {
  unsigned r;
  asm("v_cvt_pk_bf16_f32 %0, %1, %2" : "=v"(r) : "v"(lo), "v"(hi));
  return r;
}
__device__ __forceinline__ unsigned char f2fp8(float f) {
  return (unsigned char)(__builtin_amdgcn_cvt_pk_fp8_f32(f, f, 0, false) & 0xff);
}

// ---- pass 1a: per-block 256-bin LDS histograms of dst>>9 and src>>9 ----
// Writes raw per-block counts AND accumulates global per-bucket totals.
// Tail blocks (blockIdx >= PB): Wt[n][k] = bf16(W1[k][n]) + Z8 zero row.
__global__ __launch_bounds__(256) void k_part1a(const int* __restrict__ src, const int* __restrict__ dst,
                                                const int* __restrict__ gid,
                                                unsigned* __restrict__ rawD, unsigned* __restrict__ rawS,
                                                unsigned* __restrict__ tot,
                                                int* __restrict__ gcnt,
                                                const float* __restrict__ W1, unsigned short* __restrict__ Wt,
                                                unsigned char* __restrict__ zrow,
                                                int E, int N, int G) {
  if (blockIdx.x >= PB) {          // wprep tail: 64 blocks x 2 rows
    int wb = blockIdx.x - PB;
    int n = wb * 2 + (threadIdx.x >> 7), k = threadIdx.x & 127;
    Wt[n * 128 + k] = f2bf(W1[k * 128 + n]);
    if (wb == 0 && threadIdx.x < 128) zrow[threadIdx.x] = 0;
    return;
  }
  __shared__ unsigned hD[256], hS[256];
  __shared__ int h64[64];
  hD[threadIdx.x] = 0; hS[threadIdx.x] = 0;
  if (threadIdx.x < 64) h64[threadIdx.x] = 0;
  __syncthreads();
  int chunk = (E + PB - 1) / PB;
  int e0 = blockIdx.x * chunk, e1 = min(E, e0 + chunk);
  for (int e = e0 + threadIdx.x; e < e1; e += 256) {
    atomicAdd(&hD[(unsigned)dst[e] >> 9], 1u);
    atomicAdd(&hS[(unsigned)src[e] >> 9], 1u);
  }
  int stride = PB * 256;
  for (int i = blockIdx.x * 256 + threadIdx.x; i < N; i += stride)
    atomicAdd(&h64[gid[i]], 1);
  __syncthreads();
  unsigned vd = hD[threadIdx.x], vs = hS[threadIdx.x];
  rawD[blockIdx.x * 256 + threadIdx.x] = vd;
  rawS[blockIdx.x * 256 + threadIdx.x] = vs;
  if (vd) atomicAdd(&tot[threadIdx.x], vd);
  if (vs) atomicAdd(&tot[256 + threadIdx.x], vs);
  if (threadIdx.x < (unsigned)G) {
    int v = h64[threadIdx.x];
    if (v) atomicAdd(&gcnt[threadIdx.x], v);
  }
}

// ---- pscanB: one block — scan bucket totals, seed global cursors ----
__global__ __launch_bounds__(256) void k_pscanB(const unsigned* __restrict__ tot,
                                                int* __restrict__ bsD, int* __restrict__ bsS,
                                                unsigned* __restrict__ curD, unsigned* __restrict__ curS) {
  __shared__ unsigned s[256];
  int t = threadIdx.x;
#pragma unroll
  for (int table = 0; table < 2; ++table) {
    int* bs = table ? bsS : bsD;
    unsigned* cur = table ? curS : curD;
    unsigned v = tot[table * 256 + t];
    s[t] = v;
    __syncthreads();
    for (int off = 1; off < 256; off <<= 1) {
      unsigned x = (t >= off) ? s[t - off] : 0;
      __syncthreads();
      s[t] += x;
      __syncthreads();
    }
    unsigned e = s[t] - v;
    bs[t] = (int)e;
    cur[t] = e;
    if (t == 255) bs[256] = (int)s[255];
    __syncthreads();
  }
}

// ---- pass 1c v4: ONE pass over (src,dst), both tables LDS-staged;
//      per-bucket run-space claimed via global atomic cursors.
// pairD: (dst&511)<<17 | src ; pairS: (src&511)<<17 | dst   (N < 2^17)
__global__ __launch_bounds__(256) void k_part1c(const int* __restrict__ src, const int* __restrict__ dst,
                                                const unsigned* __restrict__ rawD, const unsigned* __restrict__ rawS,
                                                unsigned* __restrict__ curDg, unsigned* __restrict__ curSg,
                                                unsigned* __restrict__ pairD, unsigned* __restrict__ pairS, int E) {
  __shared__ unsigned pkD[CHK], pkS[CHK];
  __shared__ unsigned char bkD[CHK], bkS[CHK];
  __shared__ unsigned cD[256], cS[256], gbD[256], gbS[256], psc[256];
  int chunk = (E + gridDim.x - 1) / gridDim.x;
  int e0 = blockIdx.x * chunk, e1 = min(E, e0 + chunk);
  int n = e1 - e0;
  int t = threadIdx.x;
  unsigned vD = rawD[blockIdx.x * 256 + t];
  unsigned baseD = atomicAdd(&curDg[t], vD);   // claim run space (issued early)
  psc[t] = vD;
  __syncthreads();
  for (int off = 1; off < 256; off <<= 1) {
    unsigned x = (t >= off) ? psc[t - off] : 0;
    __syncthreads();
    psc[t] += x;
    __syncthreads();
  }
  unsigned exD = psc[t] - vD;
  cD[t] = exD;
  gbD[t] = baseD - exD;
  __syncthreads();
  unsigned vS = rawS[blockIdx.x * 256 + t];
  unsigned baseS = atomicAdd(&curSg[t], vS);
  psc[t] = vS;
  __syncthreads();
  for (int off = 1; off < 256; off <<= 1) {
    unsigned x = (t >= off) ? psc[t - off] : 0;
    __syncthreads();
    psc[t] += x;
    __syncthreads();
  }
  unsigned exS = psc[t] - vS;
  cS[t] = exS;
  gbS[t] = baseS - exS;
  __syncthreads();
  for (int i = t; i < n; i += 256) {
    unsigned sv = (unsigned)src[e0 + i], dv = (unsigned)dst[e0 + i];
    unsigned bD = dv >> 9, bS = sv >> 9;
    unsigned pD = atomicAdd(&cD[bD], 1u);
    pkD[pD] = ((dv & 511u) << 17) | sv;
    bkD[pD] = (unsigned char)bD;
    unsigned pS = atomicAdd(&cS[bS], 1u);
    pkS[pS] = ((sv & 511u) << 17) | dv;
    bkS[pS] = (unsigned char)bS;
  }
  __syncthreads();
  for (int i = t; i < n; i += 256)
    pairD[gbD[bkD[i]] + i] = pkD[i];
  for (int i = t; i < n; i += 256)
    pairS[gbS[bkS[i]] + i] = pkS[i];
}

// ---- pass 2d (+norm fused +degree hist): per dst-bucket ----
__global__ __launch_bounds__(256) void k_part2d(const unsigned* __restrict__ pairD, const int* __restrict__ bsD,
                                                const int* __restrict__ gcnt, const int* __restrict__ gid,
                                                int* __restrict__ offs, float* __restrict__ ndst,
                                                uint2* __restrict__ pwg, int* __restrict__ degI,
                                                int* __restrict__ dbin,
                                                int* __restrict__ srcS, int N) {
  __shared__ unsigned hist[512], excl[512], psc[256];
  __shared__ int ldb[256];
  int k = blockIdx.x, base = k << 9;
  int b0 = bsD[k], b1 = bsD[k + 1];
  hist[threadIdx.x] = 0; hist[threadIdx.x + 256] = 0;
  ldb[threadIdx.x] = 0;
  __syncthreads();
  for (int i = b0 + threadIdx.x; i < b1; i += 256)
    atomicAdd(&hist[pairD[i] >> 17], 1u);
  __syncthreads();
  unsigned s0 = hist[2 * threadIdx.x], s1 = hist[2 * threadIdx.x + 1];
  unsigned pr = s0 + s1;
  psc[threadIdx.x] = pr;
  __syncthreads();
  for (int off = 1; off < 256; off <<= 1) {
    unsigned x = (threadIdx.x >= off) ? psc[threadIdx.x - off] : 0;
    __syncthreads();
    psc[threadIdx.x] += x;
    __syncthreads();
  }
  unsigned pex = psc[threadIdx.x] - pr;
  excl[2 * threadIdx.x] = pex;
  excl[2 * threadIdx.x + 1] = pex + s0;
  __syncthreads();
  for (int j = threadIdx.x; j < 512; j += 256) {
    int node = base + j;
    if (node <= N) offs[node] = b0 + (int)excl[j];
    if (node < N) {
      int dg = (int)hist[j];
      degI[node] = dg;
      atomicAdd(&ldb[255 - min(dg, 255)], 1);   // reversed bin -> descending sort
      float gi = (float)dg; gi = gi > 0.f ? gi : 1.f;
      float nd = rsqrtf(gi);
      ndst[node] = nd;
      float c = (float)gcnt[gid[node]]; c = c > 1.f ? c : 1.f;
      float w = nd / c;
      union { float f; unsigned u; } v; v.f = w;
      pwg[node] = make_uint2(v.u, (unsigned)gid[node]);
    }
  }
  __syncthreads();
  if (ldb[threadIdx.x]) atomicAdd(&dbin[threadIdx.x], ldb[threadIdx.x]);
  for (int i = b0 + threadIdx.x; i < b1; i += 256) {
    unsigned pkv = pairD[i];
    unsigned pos = atomicAdd(&excl[pkv >> 17], 1u);
    srcS[b0 + (int)pos] = (int)(pkv & 0x1FFFFu);
  }
}

// ---- dperm: self-scanning counting-sort scatter (dscan folded in) ----
// Every block scans dbin locally; global slot reservation via dcur (zeroed).
__global__ __launch_bounds__(256) void k_dperm(const int* __restrict__ degI, const int* __restrict__ dbin,
                                               int* __restrict__ dcur,
                                               int* __restrict__ perm, int N) {
  __shared__ int s[256], lh[256], lcur[256];
  int t = threadIdx.x, i = blockIdx.x * 256 + t;
  int v = dbin[t];
  s[t] = v;
  lh[t] = 0;
  __syncthreads();
  for (int off = 1; off < 256; off <<= 1) {
    int x = (t >= off) ? s[t - off] : 0;
    __syncthreads();
    s[t] += x;
    __syncthreads();
  }
  int excl = s[t] - v;
  int bin = 0;
  if (i < N) {
    bin = 255 - min(degI[i], 255);
    atomicAdd(&lh[bin], 1);
  }
  __syncthreads();
  int r = lh[t] ? atomicAdd(&dcur[t], lh[t]) : 0;
  lcur[t] = excl + r;
  __syncthreads();
  if (i < N) {
    int pos = atomicAdd(&lcur[bin], 1);
    perm[pos] = i;
  }
}

// ---- k_pw (fused part2s): per src-bucket — out-degree hist -> nsrc,
//      and 128 KB LDS P-tile -> blocked bf16 P_blk[(k>>3)][g][k&7] ----
__global__ __launch_bounds__(1024, 1) void k_pw(const unsigned* __restrict__ pairS, const int* __restrict__ bsS,
                                                const uint2* __restrict__ pwg,
                                                unsigned short* __restrict__ P16,
                                                float* __restrict__ nsrc, int N) {
  __shared__ float tile[512 * 64];   // 128 KB
  __shared__ unsigned hist[512];     // 2 KB
  int k = blockIdx.x, base = k << 9;
  int b0 = bsS[k], b1 = bsS[k + 1];
  for (int i = threadIdx.x; i < 512 * 64; i += 1024) tile[i] = 0.f;
  if (threadIdx.x < 512) hist[threadIdx.x] = 0;
  __syncthreads();
  for (int i = b0 + threadIdx.x; i < b1; i += 1024) {
    unsigned pkv = pairS[i];
    unsigned dv = pkv & 0x1FFFFu;
    unsigned sloc = pkv >> 17;
    atomicAdd(&hist[sloc], 1u);
    uint2 u = pwg[dv];
    union { unsigned u; float f; } w; w.u = u.x;
    atomicAdd(&tile[sloc * 64 + u.y], w.f);
  }
  __syncthreads();
  if (threadIdx.x < 512) {
    int node = base + threadIdx.x;
    if (node < N) {
      float g = (float)hist[threadIdx.x]; g = g > 0.f ? g : 1.f;
      nsrc[node] = rsqrtf(g);
    }
  }
  for (int grp = threadIdx.x; grp < 4096; grp += 1024) {
    int qb = grp >> 6, g = grp & 63;
    unsigned w0 = cvt_pk_bf16(tile[(qb * 8 + 0) * 64 + g], tile[(qb * 8 + 1) * 64 + g]);
    unsigned w1 = cvt_pk_bf16(tile[(qb * 8 + 2) * 64 + g], tile[(qb * 8 + 3) * 64 + g]);
    unsigned w2 = cvt_pk_bf16(tile[(qb * 8 + 4) * 64 + g], tile[(qb * 8 + 5) * 64 + g]);
    unsigned w3 = cvt_pk_bf16(tile[(qb * 8 + 6) * 64 + g], tile[(qb * 8 + 7) * 64 + g]);
    uint4 o = make_uint4(w0, w1, w2, w3);
    *(uint4*)(P16 + ((size_t)(base >> 3) + qb) * 512 + g * 8) = o;
  }
}

// ---- GEMM1 v4 (MFMA): Z8 = fp8( (X @ W1) * nsrc[row] ), 2 tiles/block ----
// Both tiles' X loads issued up-front (in flight across Wt staging+barrier);
// Wt staged once per block with XOR swizzle.
__global__ __launch_bounds__(512) void k_gemm1(const float* __restrict__ X, const unsigned short* __restrict__ Wt,
                                               const float* __restrict__ nsrc,
                                               unsigned char* __restrict__ Z8, int N, int ntiles) {
  __shared__ unsigned short Wl[128 * 128];   // 32 KB
  int wave = threadIdx.x >> 6, lane = threadIdx.x & 63;
  int quad = lane >> 4, l16 = lane & 15;
  int t0 = blockIdx.x * 2, t1 = t0 + 1;
  bool has1 = t1 < ntiles;
  int row0a = t0 * 128 + wave * 16;
  int row0b = t1 * 128 + wave * 16;
  int arowa = row0a + l16; if (arowa >= N) arowa = N - 1;
  int arowb = row0b + l16; if (arowb >= N) arowb = N - 1;
  const float* xra = X + (size_t)arowa * 128 + quad * 8;
  const float* xrb = X + (size_t)arowb * 128 + quad * 8;
  // issue ALL X loads for both tiles first (16 float4 in flight)
  float4 xa[8], xb[8];
#pragma unroll
  for (int kbi = 0; kbi < 4; ++kbi) {
    xa[2 * kbi]     = *(const float4*)(xra + kbi * 32);
    xa[2 * kbi + 1] = *(const float4*)(xra + kbi * 32 + 4);
    xb[2 * kbi]     = *(const float4*)(xrb + kbi * 32);
    xb[2 * kbi + 1] = *(const float4*)(xrb + kbi * 32 + 4);
  }
  // hoist nsrc for both epilogues
  int rbasea = row0a + quad * 4, rbaseb = row0b + quad * 4;
  float sca[4], scb[4];
#pragma unroll
  for (int r = 0; r < 4; ++r) {
    int ra = rbasea + r; if (ra >= N) ra = N - 1;
    int rb = rbaseb + r; if (rb >= N) rb = N - 1;
    sca[r] = nsrc[ra];
    scb[r] = nsrc[rb];
  }
  // stage Wt -> LDS with XOR swizzle: 2048 uint4, 4 per thread
  for (int i = threadIdx.x; i < 2048; i += 512) {
    int wrow = i >> 4, sgrp = i & 15;
    *(uint4*)(Wl + wrow * 128 + ((sgrp ^ (wrow & 15)) << 3)) = ((const uint4*)Wt)[i];
  }
  __syncthreads();
  // ---- tile 0 ----
  f32x4 acc[8];
#pragma unroll
  for (int i = 0; i < 8; ++i) acc[i] = (f32x4){0.f, 0.f, 0.f, 0.f};
#pragma unroll
  for (int kbi = 0; kbi < 4; ++kbi) {
    float4 x0 = xa[2 * kbi], x1 = xa[2 * kbi + 1];
    union { unsigned u[4]; bf16x8 v; } A;
    A.u[0] = cvt_pk_bf16(x0.x, x0.y);
    A.u[1] = cvt_pk_bf16(x0.z, x0.w);
    A.u[2] = cvt_pk_bf16(x1.x, x1.y);
    A.u[3] = cvt_pk_bf16(x1.z, x1.w);
#pragma unroll
    for (int nt = 0; nt < 8; ++nt) {
      bf16x8 b = *(const bf16x8*)(Wl + (nt * 16 + l16) * 128 + (((kbi * 4 + quad) ^ l16) << 3));
      acc[nt] = __builtin_amdgcn_mfma_f32_16x16x32_bf16(A.v, b, acc[nt], 0, 0, 0);
    }
  }
#pragma unroll
  for (int r = 0; r < 4; ++r) {
    int row = rbasea + r;
    if (row < N) {
      float s = sca[r];
#pragma unroll
      for (int nt = 0; nt < 8; ++nt)
        Z8[(size_t)row * 128 + nt * 16 + l16] = f2fp8(acc[nt][r] * s);
    }
  }
  // ---- tile 1 ----
  if (!has1) return;
#pragma unroll
  for (int i = 0; i < 8; ++i) acc[i] = (f32x4){0.f, 0.f, 0.f, 0.f};
#pragma unroll
  for (int kbi = 0; kbi < 4; ++kbi) {
    float4 x0 = xb[2 * kbi], x1 = xb[2 * kbi + 1];
    union { unsigned u[4]; bf16x8 v; } A;
    A.u[0] = cvt_pk_bf16(x0.x, x0.y);
    A.u[1] = cvt_pk_bf16(x0.z, x0.w);
    A.u[2] = cvt_pk_bf16(x1.x, x1.y);
    A.u[3] = cvt_pk_bf16(x1.z, x1.w);
#pragma unroll
    for (int nt = 0; nt < 8; ++nt) {
      bf16x8 b = *(const bf16x8*)(Wl + (nt * 16 + l16) * 128 + (((kbi * 4 + quad) ^ l16) << 3));
      acc[nt] = __builtin_amdgcn_mfma_f32_16x16x32_bf16(A.v, b, acc[nt], 0, 0, 0);
    }
  }
#pragma unroll
  for (int r = 0; r < 4; ++r) {
    int row = rbaseb + r;
    if (row < N) {
      float s = scb[r];
#pragma unroll
      for (int nt = 0; nt < 8; ++nt)
        Z8[(size_t)row * 128 + nt * 16 + l16] = f2fp8(acc[nt][r] * s);
    }
  }
}

// ---- layer1 v7: persistent grid-stride; octet owns a dst (8 dsts/wave) ----
#define ACC16(u) do {                                             \
    c0 += __builtin_amdgcn_cvt_pk_f32_fp8((u).x, false);          \
    c1 += __builtin_amdgcn_cvt_pk_f32_fp8((u).x, true);           \
    c2 += __builtin_amdgcn_cvt_pk_f32_fp8((u).y, false);          \
    c3 += __builtin_amdgcn_cvt_pk_f32_fp8((u).y, true);           \
    c4 += __builtin_amdgcn_cvt_pk_f32_fp8((u).z, false);          \
    c5 += __builtin_amdgcn_cvt_pk_f32_fp8((u).z, true);           \
    c6 += __builtin_amdgcn_cvt_pk_f32_fp8((u).w, false);          \
    c7 += __builtin_amdgcn_cvt_pk_f32_fp8((u).w, true);           \
  } while (0)

__global__ __launch_bounds__(256) void k_layer1(const unsigned char* __restrict__ Z8,
                                                const int* __restrict__ offs, const int* __restrict__ srcS,
                                                const int* __restrict__ perm,
                                                const float* __restrict__ b1,
                                                const float* __restrict__ nsrc, const float* __restrict__ ndst,
                                                unsigned short* __restrict__ Hb, int N) {
  int lane = threadIdx.x & 63;
  int oct = lane >> 3, l8 = lane & 7;
  const int f = l8 * 16;                 // 16 channels per lane
  const unsigned char* zb = Z8 + f;
  int gstride = gridDim.x * 32;
  for (int base = blockIdx.x * 32; base < N; base += gstride) {
    int dd = base + (threadIdx.x >> 6) * 8 + oct;
    bool live = dd < N;
    int pd = perm[live ? dd : 0];
    int start = offs[pd];
    int end = live ? offs[pd + 1] : start;
    float nd = ndst[pd], ns = nsrc[pd];
    f32x2 c0 = {0.f, 0.f}, c1 = {0.f, 0.f}, c2 = {0.f, 0.f}, c3 = {0.f, 0.f};
    f32x2 c4 = {0.f, 0.f}, c5 = {0.f, 0.f}, c6 = {0.f, 0.f}, c7 = {0.f, 0.f};
    int e = start;
    int rem = end - start;
    int s0 = N, s1 = N, s2 = N, s3 = N;
    if (rem > 0) s0 = srcS[e];
    if (rem > 1) s1 = srcS[e + 1];
    if (rem > 2) s2 = srcS[e + 2];
    if (rem > 3) s3 = srcS[e + 3];
    while (__any(rem > 0)) {
      uint4 u0 = *(const uint4*)(zb + ((size_t)s0 << 7));
      uint4 u1 = *(const uint4*)(zb + ((size_t)s1 << 7));
      uint4 u2 = *(const uint4*)(zb + ((size_t)s2 << 7));
      uint4 u3 = *(const uint4*)(zb + ((size_t)s3 << 7));
      int n0 = N, n1 = N, n2 = N, n3 = N;
      if (rem > 4) n0 = srcS[e + 4];      // prefetch next 4 before consuming
      if (rem > 5) n1 = srcS[e + 5];
      if (rem > 6) n2 = srcS[e + 6];
      if (rem > 7) n3 = srcS[e + 7];
      ACC16(u0);
      ACC16(u1);
      ACC16(u2);
      ACC16(u3);
      s0 = n0; s1 = n1; s2 = n2; s3 = n3;
      e += 4;
      rem -= 4;
    }
    if (live) {
      float4 bv0 = *(const float4*)(b1 + f);
      float4 bv1 = *(const float4*)(b1 + f + 4);
      float4 bv2 = *(const float4*)(b1 + f + 8);
      float4 bv3 = *(const float4*)(b1 + f + 12);
      float h0 = fmaxf(fmaf(nd, c0[0], bv0.x), 0.f) * ns;
      float h1 = fmaxf(fmaf(nd, c0[1], bv0.y), 0.f) * ns;
      float h2 = fmaxf(fmaf(nd, c1[0], bv0.z), 0.f) * ns;
      float h3 = fmaxf(fmaf(nd, c1[1], bv0.w), 0.f) * ns;
      float h4 = fmaxf(fmaf(nd, c2[0], bv1.x), 0.f) * ns;
      float h5 = fmaxf(fmaf(nd, c2[1], bv1.y), 0.f) * ns;
      float h6 = fmaxf(fmaf(nd, c3[0], bv1.z), 0.f) * ns;
      float h7 = fmaxf(fmaf(nd, c3[1], bv1.w), 0.f) * ns;
      float h8 = fmaxf(fmaf(nd, c4[0], bv2.x), 0.f) * ns;
      float h9 = fmaxf(fmaf(nd, c4[1], bv2.y), 0.f) * ns;
      float hA = fmaxf(fmaf(nd, c5[0], bv2.z), 0.f) * ns;
      float hB = fmaxf(fmaf(nd, c5[1], bv2.w), 0.f) * ns;
      float hC = fmaxf(fmaf(nd, c6[0], bv3.x), 0.f) * ns;
      float hD = fmaxf(fmaf(nd, c6[1], bv3.y), 0.f) * ns;
      float hE = fmaxf(fmaf(nd, c7[0], bv3.z), 0.f) * ns;
      float hF = fmaxf(fmaf(nd, c7[1], bv3.w), 0.f) * ns;
      unsigned short* hrow = Hb + (size_t)pd * 128 + f;
      *(uint4*)hrow = make_uint4(cvt_pk_bf16(h0, h1), cvt_pk_bf16(h2, h3),
                                 cvt_pk_bf16(h4, h5), cvt_pk_bf16(h6, h7));
      *(uint4*)(hrow + 8) = make_uint4(cvt_pk_bf16(h8, h9), cvt_pk_bf16(hA, hB),
                                       cvt_pk_bf16(hC, hD), cvt_pk_bf16(hE, hF));
    }
  }
}

// ---- k_poolgemm (MFMA): pooled += P_blk^T · H  (split-K, bf16, f32 acc) ----
__global__ __launch_bounds__(256) void k_poolgemm(const unsigned short* __restrict__ P16,
                                                  const unsigned short* __restrict__ Hb,
                                                  float* __restrict__ pooled, int N, int Kpad, int chunk) {
  __shared__ unsigned short Hl[KC * 128];   // 8 KB, 16-short groups XOR-swizzled by (row>>3)
  int t = threadIdx.x;
  int r0 = blockIdx.x * chunk;
  int r1 = min(Kpad, r0 + chunk);
  int wv = t >> 6, lane = t & 63, quad = lane >> 4, l16 = lane & 15;
  f32x4 acc[8];
#pragma unroll
  for (int i = 0; i < 8; ++i) acc[i] = (f32x4){0.f, 0.f, 0.f, 0.f};
  for (int rb = r0; rb < r1; rb += KC) {
    int r = t >> 3, c = (t & 7) * 16;
    int cs = c ^ ((r >> 3) * 16);        // swizzle 16-short group by row-octet
    int row = rb + r;
    if (row < N) {
      const uint4* srcp = (const uint4*)(Hb + (size_t)row * 128 + c);
      *(uint4*)(Hl + r * 128 + cs) = srcp[0];
      *(uint4*)(Hl + r * 128 + cs + 8) = srcp[1];
    } else {
      uint4 z = make_uint4(0, 0, 0, 0);
      *(uint4*)(Hl + r * 128 + cs) = z;
      *(uint4*)(Hl + r * 128 + cs + 8) = z;
    }
    __syncthreads();
    bf16x8 a = *(const bf16x8*)(P16 + ((size_t)(rb >> 3) + quad) * 512 + (wv * 16 + l16) * 8);
#pragma unroll
    for (int ft = 0; ft < 8; ++ft) {
      bf16x8 b;
#pragma unroll
      for (int j = 0; j < 8; ++j) {
        int rr = quad * 8 + j;
        b[j] = (short)Hl[rr * 128 + ((ft ^ (rr >> 3)) * 16) + l16];
      }
      acc[ft] = __builtin_amdgcn_mfma_f32_16x16x32_bf16(a, b, acc[ft], 0, 0, 0);
    }
    __syncthreads();
  }
#pragma unroll
  for (int ft = 0; ft < 8; ++ft)
#pragma unroll
    for (int rg = 0; rg < 4; ++rg)
      unsafeAtomicAdd(&pooled[(wv * 16 + quad * 4 + rg) * DD + ft * 16 + l16], acc[ft][rg]);
}

// ---- out = pooled @ W2 + b2 ----
__global__ __launch_bounds__(128) void k_out(const float* __restrict__ pooled, const float* __restrict__ W2,
                                             const float* __restrict__ b2, float* __restrict__ out) {
  __shared__ float p[DD];
  int g = blockIdx.x, d = threadIdx.x;
  p[d] = pooled[g * DD + d];
  __syncthreads();
  float a = b2[d];
#pragma unroll 4
  for (int k = 0; k < DD; ++k) a = fmaf(p[k], W2[k * DD + d], a);
  out[g * DD + d] = a;
}

extern "C" void kernel_launch(void* const* d_in, const int* in_sizes, int n_in,
                              void* d_out, int out_size, void* d_ws, size_t ws_size,
                              hipStream_t stream) {
  const float* X  = (const float*)d_in[0];
  const float* W1 = (const float*)d_in[1];
  const float* b1 = (const float*)d_in[2];
  const float* W2 = (const float*)d_in[3];
  const float* b2 = (const float*)d_in[4];
  const int* src  = (const int*)d_in[5];
  const int* dst  = (const int*)d_in[6];
  const int* gid  = (const int*)d_in[7];
  int E = in_sizes[5];
  int N = in_sizes[7];
  int G = out_size / DD;   // 64
  int nb = (N >> 9) + 1;   // node buckets
  int Kpad = nb << 9;
  int chunk = ((Kpad + GB * KC - 1) / (GB * KC)) * KC;
  int ntiles = (N + 127) / 128;

  char* w = (char*)d_ws;
  size_t o = 0;
  auto carve = [&](size_t bytes) { char* p = w + o; o += (bytes + 255) & ~(size_t)255; return p; };
  // zero-init region
  int*   gcnt   = (int*)  carve((size_t)G * 4);
  float* pooled = (float*)carve((size_t)G * DD * 4);
  int*   dbin   = (int*)  carve(256 * 4);
  unsigned* tot = (unsigned*)carve(512 * 4);
  int*   dcur   = (int*)  carve(256 * 4);
  size_t zeroBytes = o;
  // rest (fully written before read)
  unsigned* rawD  = (unsigned*)carve((size_t)PB * 256 * 4);
  unsigned* rawS  = (unsigned*)carve((size_t)PB * 256 * 4);
  int*   bsD    = (int*)  carve(257 * 4);
  int*   bsS    = (int*)  carve(257 * 4);
  unsigned* curD = (unsigned*)carve(256 * 4);
  unsigned* curS = (unsigned*)carve(256 * 4);
  unsigned* pairD = (unsigned*)carve((size_t)E * 4);
  unsigned* pairS = (unsigned*)carve((size_t)E * 4);
  int*   srcS   = (int*)  carve((size_t)E * 4);
  int*   offs   = (int*)  carve((size_t)(N + 1) * 4);
  int*   degI   = (int*)  carve((size_t)N * 4);
  int*   perm   = (int*)  carve((size_t)N * 4);
  float* nsrc   = (float*)carve((size_t)N * 4);
  float* ndst   = (float*)carve((size_t)N * 4);
  uint2* pwg    = (uint2*)carve((size_t)N * 8);
  unsigned short* Wt = (unsigned short*)carve(128 * 128 * 2);
  unsigned char*  Z8 = (unsigned char*)carve((size_t)(N + 1) * DD);   // fp8, +1 zero row
  unsigned short* Hb = (unsigned short*)carve((size_t)N * DD * 2);
  unsigned short* P16 = (unsigned short*)carve((size_t)Kpad * 64 * 2);  // blocked bf16

  hipMemsetAsync(d_ws, 0, zeroBytes, stream);

  k_part1a<<<PB + 64, 256, 0, stream>>>(src, dst, gid, rawD, rawS, tot, gcnt,
                                        W1, Wt, Z8 + (size_t)N * DD, E, N, G);
  k_pscanB<<<1, 256, 0, stream>>>(tot, bsD, bsS, curD, curS);
  k_part1c<<<PB, 256, 0, stream>>>(src, dst, rawD, rawS, curD, curS, pairD, pairS, E);
  k_part2d<<<nb, 256, 0, stream>>>(pairD, bsD, gcnt, gid, offs, ndst, pwg, degI, dbin, srcS, N);
  k_dperm<<<(N + 255) / 256, 256, 0, stream>>>(degI, dbin, dcur, perm, N);
  k_pw<<<nb, 1024, 0, stream>>>(pairS, bsS, pwg, P16, nsrc, N);
  k_gemm1<<<(ntiles + 1) / 2, 512, 0, stream>>>(X, Wt, nsrc, Z8, N, ntiles);
  k_layer1<<<2048, 256, 0, stream>>>(Z8, offs, srcS, perm, b1, nsrc, ndst, Hb, N);
  k_poolgemm<<<GB, 256, 0, stream>>>(P16, Hb, pooled, N, Kpad, chunk);
  k_out<<<G, DD, 0, stream>>>(pooled, W2, b2, (float*)d_out);
}

// Round 9
// 275.949 us; speedup vs baseline: 1.0065x; 1.0065x over previous
//
#include <hip/hip_runtime.h>
#include <cstdint>

// GCN via radix partition (bucket = node>>9), packed u32 edge records.
// part1a: edge histograms (block-local -> rawD/rawS, global tot via atomics)
//         + gcnt + wprep tail blocks (W1 transpose, Z8 zero row).
// pscanB: scan tot -> bsD/bsS, seed global bucket cursors curD/curS.
// part1c v4: single pass, both tables LDS-staged; block run-space claimed
//            via ONE global atomicAdd per bucket (pscanA deleted).
// part2d: norm fused + degree histogram for balance-sort.
// dperm: self-scanning counting-sort scatter (dscan folded in).
// gemm1 v3 (REVERT from v4): 1x128-row tile/block, X loads hoisted.
// layer1 v7: degree-DESC perm, octet owns a dst, uint4 gathers, persistent
//            grid-stride, 1024 blocks (REVERT from 2048).

#define DD 128
#define PB 512    // partition pass-1 blocks
#define GB 384    // poolgemm split-K blocks
#define KC 32     // poolgemm K-chunk
#define CHK 3200  // max edges per part1c block

typedef __attribute__((ext_vector_type(8))) short bf16x8;
typedef __attribute__((ext_vector_type(4))) float f32x4;
typedef __attribute__((ext_vector_type(2))) float f32x2;

__device__ __forceinline__ unsigned short f2bf(float f) {
  union { float f; unsigned u; } v; v.f = f;
  unsigned r = (v.u + 0x7fff + ((v.u >> 16) & 1)) >> 16;   // round-nearest-even
  return (unsigned short)r;
}
__device__ __forceinline__ unsigned cvt_pk_bf16(float lo, float hi) {
  unsigned r;
  asm("v_cvt_pk_bf16_f32 %0, %1, %2" : "=v"(r) : "v"(lo), "v"(hi));
  return r;
}
__device__ __forceinline__ unsigned char f2fp8(float f) {
  return (unsigned char)(__builtin_amdgcn_cvt_pk_fp8_f32(f, f, 0, false) & 0xff);
}

// ---- pass 1a: per-block 256-bin LDS histograms of dst>>9 and src>>9 ----
// Writes raw per-block counts AND accumulates global per-bucket totals.
// Tail blocks (blockIdx >= PB): Wt[n][k] = bf16(W1[k][n]) + Z8 zero row.
__global__ __launch_bounds__(256) void k_part1a(const int* __restrict__ src, const int* __restrict__ dst,
                                                const int* __restrict__ gid,
                                                unsigned* __restrict__ rawD, unsigned* __restrict__ rawS,
                                                unsigned* __restrict__ tot,
                                                int* __restrict__ gcnt,
                                                const float* __restrict__ W1, unsigned short* __restrict__ Wt,
                                                unsigned char* __restrict__ zrow,
                                                int E, int N, int G) {
  if (blockIdx.x >= PB) {          // wprep tail: 64 blocks x 2 rows
    int wb = blockIdx.x - PB;
    int n = wb * 2 + (threadIdx.x >> 7), k = threadIdx.x & 127;
    Wt[n * 128 + k] = f2bf(W1[k * 128 + n]);
    if (wb == 0 && threadIdx.x < 128) zrow[threadIdx.x] = 0;
    return;
  }
  __shared__ unsigned hD[256], hS[256];
  __shared__ int h64[64];
  hD[threadIdx.x] = 0; hS[threadIdx.x] = 0;
  if (threadIdx.x < 64) h64[threadIdx.x] = 0;
  __syncthreads();
  int chunk = (E + PB - 1) / PB;
  int e0 = blockIdx.x * chunk, e1 = min(E, e0 + chunk);
  for (int e = e0 + threadIdx.x; e < e1; e += 256) {
    atomicAdd(&hD[(unsigned)dst[e] >> 9], 1u);
    atomicAdd(&hS[(unsigned)src[e] >> 9], 1u);
  }
  int stride = PB * 256;
  for (int i = blockIdx.x * 256 + threadIdx.x; i < N; i += stride)
    atomicAdd(&h64[gid[i]], 1);
  __syncthreads();
  unsigned vd = hD[threadIdx.x], vs = hS[threadIdx.x];
  rawD[blockIdx.x * 256 + threadIdx.x] = vd;
  rawS[blockIdx.x * 256 + threadIdx.x] = vs;
  if (vd) atomicAdd(&tot[threadIdx.x], vd);
  if (vs) atomicAdd(&tot[256 + threadIdx.x], vs);
  if (threadIdx.x < (unsigned)G) {
    int v = h64[threadIdx.x];
    if (v) atomicAdd(&gcnt[threadIdx.x], v);
  }
}

// ---- pscanB: one block — scan bucket totals, seed global cursors ----
__global__ __launch_bounds__(256) void k_pscanB(const unsigned* __restrict__ tot,
                                                int* __restrict__ bsD, int* __restrict__ bsS,
                                                unsigned* __restrict__ curD, unsigned* __restrict__ curS) {
  __shared__ unsigned s[256];
  int t = threadIdx.x;
#pragma unroll
  for (int table = 0; table < 2; ++table) {
    int* bs = table ? bsS : bsD;
    unsigned* cur = table ? curS : curD;
    unsigned v = tot[table * 256 + t];
    s[t] = v;
    __syncthreads();
    for (int off = 1; off < 256; off <<= 1) {
      unsigned x = (t >= off) ? s[t - off] : 0;
      __syncthreads();
      s[t] += x;
      __syncthreads();
    }
    unsigned e = s[t] - v;
    bs[t] = (int)e;
    cur[t] = e;
    if (t == 255) bs[256] = (int)s[255];
    __syncthreads();
  }
}

// ---- pass 1c v4: ONE pass over (src,dst), both tables LDS-staged;
//      per-bucket run-space claimed via global atomic cursors.
// pairD: (dst&511)<<17 | src ; pairS: (src&511)<<17 | dst   (N < 2^17)
__global__ __launch_bounds__(256) void k_part1c(const int* __restrict__ src, const int* __restrict__ dst,
                                                const unsigned* __restrict__ rawD, const unsigned* __restrict__ rawS,
                                                unsigned* __restrict__ curDg, unsigned* __restrict__ curSg,
                                                unsigned* __restrict__ pairD, unsigned* __restrict__ pairS, int E) {
  __shared__ unsigned pkD[CHK], pkS[CHK];
  __shared__ unsigned char bkD[CHK], bkS[CHK];
  __shared__ unsigned cD[256], cS[256], gbD[256], gbS[256], psc[256];
  int chunk = (E + gridDim.x - 1) / gridDim.x;
  int e0 = blockIdx.x * chunk, e1 = min(E, e0 + chunk);
  int n = e1 - e0;
  int t = threadIdx.x;
  unsigned vD = rawD[blockIdx.x * 256 + t];
  unsigned baseD = atomicAdd(&curDg[t], vD);   // claim run space (issued early)
  psc[t] = vD;
  __syncthreads();
  for (int off = 1; off < 256; off <<= 1) {
    unsigned x = (t >= off) ? psc[t - off] : 0;
    __syncthreads();
    psc[t] += x;
    __syncthreads();
  }
  unsigned exD = psc[t] - vD;
  cD[t] = exD;
  gbD[t] = baseD - exD;
  __syncthreads();
  unsigned vS = rawS[blockIdx.x * 256 + t];
  unsigned baseS = atomicAdd(&curSg[t], vS);
  psc[t] = vS;
  __syncthreads();
  for (int off = 1; off < 256; off <<= 1) {
    unsigned x = (t >= off) ? psc[t - off] : 0;
    __syncthreads();
    psc[t] += x;
    __syncthreads();
  }
  unsigned exS = psc[t] - vS;
  cS[t] = exS;
  gbS[t] = baseS - exS;
  __syncthreads();
  for (int i = t; i < n; i += 256) {
    unsigned sv = (unsigned)src[e0 + i], dv = (unsigned)dst[e0 + i];
    unsigned bD = dv >> 9, bS = sv >> 9;
    unsigned pD = atomicAdd(&cD[bD], 1u);
    pkD[pD] = ((dv & 511u) << 17) | sv;
    bkD[pD] = (unsigned char)bD;
    unsigned pS = atomicAdd(&cS[bS], 1u);
    pkS[pS] = ((sv & 511u) << 17) | dv;
    bkS[pS] = (unsigned char)bS;
  }
  __syncthreads();
  for (int i = t; i < n; i += 256)
    pairD[gbD[bkD[i]] + i] = pkD[i];
  for (int i = t; i < n; i += 256)
    pairS[gbS[bkS[i]] + i] = pkS[i];
}

// ---- pass 2d (+norm fused +degree hist): per dst-bucket ----
__global__ __launch_bounds__(256) void k_part2d(const unsigned* __restrict__ pairD, const int* __restrict__ bsD,
                                                const int* __restrict__ gcnt, const int* __restrict__ gid,
                                                int* __restrict__ offs, float* __restrict__ ndst,
                                                uint2* __restrict__ pwg, int* __restrict__ degI,
                                                int* __restrict__ dbin,
                                                int* __restrict__ srcS, int N) {
  __shared__ unsigned hist[512], excl[512], psc[256];
  __shared__ int ldb[256];
  int k = blockIdx.x, base = k << 9;
  int b0 = bsD[k], b1 = bsD[k + 1];
  hist[threadIdx.x] = 0; hist[threadIdx.x + 256] = 0;
  ldb[threadIdx.x] = 0;
  __syncthreads();
  for (int i = b0 + threadIdx.x; i < b1; i += 256)
    atomicAdd(&hist[pairD[i] >> 17], 1u);
  __syncthreads();
  unsigned s0 = hist[2 * threadIdx.x], s1 = hist[2 * threadIdx.x + 1];
  unsigned pr = s0 + s1;
  psc[threadIdx.x] = pr;
  __syncthreads();
  for (int off = 1; off < 256; off <<= 1) {
    unsigned x = (threadIdx.x >= off) ? psc[threadIdx.x - off] : 0;
    __syncthreads();
    psc[threadIdx.x] += x;
    __syncthreads();
  }
  unsigned pex = psc[threadIdx.x] - pr;
  excl[2 * threadIdx.x] = pex;
  excl[2 * threadIdx.x + 1] = pex + s0;
  __syncthreads();
  for (int j = threadIdx.x; j < 512; j += 256) {
    int node = base + j;
    if (node <= N) offs[node] = b0 + (int)excl[j];
    if (node < N) {
      int dg = (int)hist[j];
      degI[node] = dg;
      atomicAdd(&ldb[255 - min(dg, 255)], 1);   // reversed bin -> descending sort
      float gi = (float)dg; gi = gi > 0.f ? gi : 1.f;
      float nd = rsqrtf(gi);
      ndst[node] = nd;
      float c = (float)gcnt[gid[node]]; c = c > 1.f ? c : 1.f;
      float w = nd / c;
      union { float f; unsigned u; } v; v.f = w;
      pwg[node] = make_uint2(v.u, (unsigned)gid[node]);
    }
  }
  __syncthreads();
  if (ldb[threadIdx.x]) atomicAdd(&dbin[threadIdx.x], ldb[threadIdx.x]);
  for (int i = b0 + threadIdx.x; i < b1; i += 256) {
    unsigned pkv = pairD[i];
    unsigned pos = atomicAdd(&excl[pkv >> 17], 1u);
    srcS[b0 + (int)pos] = (int)(pkv & 0x1FFFFu);
  }
}

// ---- dperm: self-scanning counting-sort scatter (dscan folded in) ----
__global__ __launch_bounds__(256) void k_dperm(const int* __restrict__ degI, const int* __restrict__ dbin,
                                               int* __restrict__ dcur,
                                               int* __restrict__ perm, int N) {
  __shared__ int s[256], lh[256], lcur[256];
  int t = threadIdx.x, i = blockIdx.x * 256 + t;
  int v = dbin[t];
  s[t] = v;
  lh[t] = 0;
  __syncthreads();
  for (int off = 1; off < 256; off <<= 1) {
    int x = (t >= off) ? s[t - off] : 0;
    __syncthreads();
    s[t] += x;
    __syncthreads();
  }
  int excl = s[t] - v;
  int bin = 0;
  if (i < N) {
    bin = 255 - min(degI[i], 255);
    atomicAdd(&lh[bin], 1);
  }
  __syncthreads();
  int r = lh[t] ? atomicAdd(&dcur[t], lh[t]) : 0;
  lcur[t] = excl + r;
  __syncthreads();
  if (i < N) {
    int pos = atomicAdd(&lcur[bin], 1);
    perm[pos] = i;
  }
}

// ---- k_pw (fused part2s): per src-bucket — out-degree hist -> nsrc,
//      and 128 KB LDS P-tile -> blocked bf16 P_blk[(k>>3)][g][k&7] ----
__global__ __launch_bounds__(1024, 1) void k_pw(const unsigned* __restrict__ pairS, const int* __restrict__ bsS,
                                                const uint2* __restrict__ pwg,
                                                unsigned short* __restrict__ P16,
                                                float* __restrict__ nsrc, int N) {
  __shared__ float tile[512 * 64];   // 128 KB
  __shared__ unsigned hist[512];     // 2 KB
  int k = blockIdx.x, base = k << 9;
  int b0 = bsS[k], b1 = bsS[k + 1];
  for (int i = threadIdx.x; i < 512 * 64; i += 1024) tile[i] = 0.f;
  if (threadIdx.x < 512) hist[threadIdx.x] = 0;
  __syncthreads();
  for (int i = b0 + threadIdx.x; i < b1; i += 1024) {
    unsigned pkv = pairS[i];
    unsigned dv = pkv & 0x1FFFFu;
    unsigned sloc = pkv >> 17;
    atomicAdd(&hist[sloc], 1u);
    uint2 u = pwg[dv];
    union { unsigned u; float f; } w; w.u = u.x;
    atomicAdd(&tile[sloc * 64 + u.y], w.f);
  }
  __syncthreads();
  if (threadIdx.x < 512) {
    int node = base + threadIdx.x;
    if (node < N) {
      float g = (float)hist[threadIdx.x]; g = g > 0.f ? g : 1.f;
      nsrc[node] = rsqrtf(g);
    }
  }
  for (int grp = threadIdx.x; grp < 4096; grp += 1024) {
    int qb = grp >> 6, g = grp & 63;
    unsigned w0 = cvt_pk_bf16(tile[(qb * 8 + 0) * 64 + g], tile[(qb * 8 + 1) * 64 + g]);
    unsigned w1 = cvt_pk_bf16(tile[(qb * 8 + 2) * 64 + g], tile[(qb * 8 + 3) * 64 + g]);
    unsigned w2 = cvt_pk_bf16(tile[(qb * 8 + 4) * 64 + g], tile[(qb * 8 + 5) * 64 + g]);
    unsigned w3 = cvt_pk_bf16(tile[(qb * 8 + 6) * 64 + g], tile[(qb * 8 + 7) * 64 + g]);
    uint4 o = make_uint4(w0, w1, w2, w3);
    *(uint4*)(P16 + ((size_t)(base >> 3) + qb) * 512 + g * 8) = o;
  }
}

// ---- GEMM1 v3 (MFMA): Z8 = fp8( (X @ W1) * nsrc[row] ) ----
// 128 rows/block (512 thr, 8 waves): Wt LDS stage amortized, X loads +
// nsrc hoisted before the MFMA loop.
__global__ __launch_bounds__(512) void k_gemm1(const float* __restrict__ X, const unsigned short* __restrict__ Wt,
                                               const float* __restrict__ nsrc,
                                               unsigned char* __restrict__ Z8, int N) {
  __shared__ unsigned short Wl[128 * 128];   // 32 KB
  int wave = threadIdx.x >> 6, lane = threadIdx.x & 63;
  int quad = lane >> 4, l16 = lane & 15;
  int row0 = blockIdx.x * 128 + wave * 16;
  int arow = row0 + l16; if (arow >= N) arow = N - 1;
  const float* xr = X + (size_t)arow * 128 + quad * 8;
  float4 xv[8];
#pragma unroll
  for (int kbi = 0; kbi < 4; ++kbi) {
    xv[2 * kbi]     = *(const float4*)(xr + kbi * 32);
    xv[2 * kbi + 1] = *(const float4*)(xr + kbi * 32 + 4);
  }
  // hoist nsrc for the epilogue rows (hidden under staging+MFMA)
  int rbase = row0 + quad * 4;
  float sc[4];
#pragma unroll
  for (int r = 0; r < 4; ++r) {
    int row = rbase + r; if (row >= N) row = N - 1;
    sc[r] = nsrc[row];
  }
  // stage Wt -> LDS with XOR swizzle: 2048 uint4, 4 per thread
  for (int i = threadIdx.x; i < 2048; i += 512) {
    int wrow = i >> 4, sgrp = i & 15;
    *(uint4*)(Wl + wrow * 128 + ((sgrp ^ (wrow & 15)) << 3)) = ((const uint4*)Wt)[i];
  }
  __syncthreads();
  f32x4 acc[8];
#pragma unroll
  for (int i = 0; i < 8; ++i) acc[i] = (f32x4){0.f, 0.f, 0.f, 0.f};
#pragma unroll
  for (int kbi = 0; kbi < 4; ++kbi) {
    float4 x0 = xv[2 * kbi], x1 = xv[2 * kbi + 1];
    union { unsigned u[4]; bf16x8 v; } A;
    A.u[0] = cvt_pk_bf16(x0.x, x0.y);
    A.u[1] = cvt_pk_bf16(x0.z, x0.w);
    A.u[2] = cvt_pk_bf16(x1.x, x1.y);
    A.u[3] = cvt_pk_bf16(x1.z, x1.w);
#pragma unroll
    for (int nt = 0; nt < 8; ++nt) {
      bf16x8 b = *(const bf16x8*)(Wl + (nt * 16 + l16) * 128 + (((kbi * 4 + quad) ^ l16) << 3));
      acc[nt] = __builtin_amdgcn_mfma_f32_16x16x32_bf16(A.v, b, acc[nt], 0, 0, 0);
    }
  }
#pragma unroll
  for (int r = 0; r < 4; ++r) {
    int row = rbase + r;
    if (row < N) {
      float s = sc[r];
#pragma unroll
      for (int nt = 0; nt < 8; ++nt)
        Z8[(size_t)row * 128 + nt * 16 + l16] = f2fp8(acc[nt][r] * s);
    }
  }
}

// ---- layer1 v7: persistent grid-stride; octet owns a dst (8 dsts/wave) ----
#define ACC16(u) do {                                             \
    c0 += __builtin_amdgcn_cvt_pk_f32_fp8((u).x, false);          \
    c1 += __builtin_amdgcn_cvt_pk_f32_fp8((u).x, true);           \
    c2 += __builtin_amdgcn_cvt_pk_f32_fp8((u).y, false);          \
    c3 += __builtin_amdgcn_cvt_pk_f32_fp8((u).y, true);           \
    c4 += __builtin_amdgcn_cvt_pk_f32_fp8((u).z, false);          \
    c5 += __builtin_amdgcn_cvt_pk_f32_fp8((u).z, true);           \
    c6 += __builtin_amdgcn_cvt_pk_f32_fp8((u).w, false);          \
    c7 += __builtin_amdgcn_cvt_pk_f32_fp8((u).w, true);           \
  } while (0)

__global__ __launch_bounds__(256) void k_layer1(const unsigned char* __restrict__ Z8,
                                                const int* __restrict__ offs, const int* __restrict__ srcS,
                                                const int* __restrict__ perm,
                                                const float* __restrict__ b1,
                                                const float* __restrict__ nsrc, const float* __restrict__ ndst,
                                                unsigned short* __restrict__ Hb, int N) {
  int lane = threadIdx.x & 63;
  int oct = lane >> 3, l8 = lane & 7;
  const int f = l8 * 16;                 // 16 channels per lane
  const unsigned char* zb = Z8 + f;
  int gstride = gridDim.x * 32;
  for (int base = blockIdx.x * 32; base < N; base += gstride) {
    int dd = base + (threadIdx.x >> 6) * 8 + oct;
    bool live = dd < N;
    int pd = perm[live ? dd : 0];
    int start = offs[pd];
    int end = live ? offs[pd + 1] : start;
    float nd = ndst[pd], ns = nsrc[pd];
    f32x2 c0 = {0.f, 0.f}, c1 = {0.f, 0.f}, c2 = {0.f, 0.f}, c3 = {0.f, 0.f};
    f32x2 c4 = {0.f, 0.f}, c5 = {0.f, 0.f}, c6 = {0.f, 0.f}, c7 = {0.f, 0.f};
    int e = start;
    int rem = end - start;
    int s0 = N, s1 = N, s2 = N, s3 = N;
    if (rem > 0) s0 = srcS[e];
    if (rem > 1) s1 = srcS[e + 1];
    if (rem > 2) s2 = srcS[e + 2];
    if (rem > 3) s3 = srcS[e + 3];
    while (__any(rem > 0)) {
      uint4 u0 = *(const uint4*)(zb + ((size_t)s0 << 7));
      uint4 u1 = *(const uint4*)(zb + ((size_t)s1 << 7));
      uint4 u2 = *(const uint4*)(zb + ((size_t)s2 << 7));
      uint4 u3 = *(const uint4*)(zb + ((size_t)s3 << 7));
      int n0 = N, n1 = N, n2 = N, n3 = N;
      if (rem > 4) n0 = srcS[e + 4];      // prefetch next 4 before consuming
      if (rem > 5) n1 = srcS[e + 5];
      if (rem > 6) n2 = srcS[e + 6];
      if (rem > 7) n3 = srcS[e + 7];
      ACC16(u0);
      ACC16(u1);
      ACC16(u2);
      ACC16(u3);
      s0 = n0; s1 = n1; s2 = n2; s3 = n3;
      e += 4;
      rem -= 4;
    }
    if (live) {
      float4 bv0 = *(const float4*)(b1 + f);
      float4 bv1 = *(const float4*)(b1 + f + 4);
      float4 bv2 = *(const float4*)(b1 + f + 8);
      float4 bv3 = *(const float4*)(b1 + f + 12);
      float h0 = fmaxf(fmaf(nd, c0[0], bv0.x), 0.f) * ns;
      float h1 = fmaxf(fmaf(nd, c0[1], bv0.y), 0.f) * ns;
      float h2 = fmaxf(fmaf(nd, c1[0], bv0.z), 0.f) * ns;
      float h3 = fmaxf(fmaf(nd, c1[1], bv0.w), 0.f) * ns;
      float h4 = fmaxf(fmaf(nd, c2[0], bv1.x), 0.f) * ns;
      float h5 = fmaxf(fmaf(nd, c2[1], bv1.y), 0.f) * ns;
      float h6 = fmaxf(fmaf(nd, c3[0], bv1.z), 0.f) * ns;
      float h7 = fmaxf(fmaf(nd, c3[1], bv1.w), 0.f) * ns;
      float h8 = fmaxf(fmaf(nd, c4[0], bv2.x), 0.f) * ns;
      float h9 = fmaxf(fmaf(nd, c4[1], bv2.y), 0.f) * ns;
      float hA = fmaxf(fmaf(nd, c5[0], bv2.z), 0.f) * ns;
      float hB = fmaxf(fmaf(nd, c5[1], bv2.w), 0.f) * ns;
      float hC = fmaxf(fmaf(nd, c6[0], bv3.x), 0.f) * ns;
      float hD = fmaxf(fmaf(nd, c6[1], bv3.y), 0.f) * ns;
      float hE = fmaxf(fmaf(nd, c7[0], bv3.z), 0.f) * ns;
      float hF = fmaxf(fmaf(nd, c7[1], bv3.w), 0.f) * ns;
      unsigned short* hrow = Hb + (size_t)pd * 128 + f;
      *(uint4*)hrow = make_uint4(cvt_pk_bf16(h0, h1), cvt_pk_bf16(h2, h3),
                                 cvt_pk_bf16(h4, h5), cvt_pk_bf16(h6, h7));
      *(uint4*)(hrow + 8) = make_uint4(cvt_pk_bf16(h8, h9), cvt_pk_bf16(hA, hB),
                                       cvt_pk_bf16(hC, hD), cvt_pk_bf16(hE, hF));
    }
  }
}

// ---- k_poolgemm (MFMA): pooled += P_blk^T · H  (split-K, bf16, f32 acc) ----
__global__ __launch_bounds__(256) void k_poolgemm(const unsigned short* __restrict__ P16,
                                                  const unsigned short* __restrict__ Hb,
                                                  float* __restrict__ pooled, int N, int Kpad, int chunk) {
  __shared__ unsigned short Hl[KC * 128];   // 8 KB, 16-short groups XOR-swizzled by (row>>3)
  int t = threadIdx.x;
  int r0 = blockIdx.x * chunk;
  int r1 = min(Kpad, r0 + chunk);
  int wv = t >> 6, lane = t & 63, quad = lane >> 4, l16 = lane & 15;
  f32x4 acc[8];
#pragma unroll
  for (int i = 0; i < 8; ++i) acc[i] = (f32x4){0.f, 0.f, 0.f, 0.f};
  for (int rb = r0; rb < r1; rb += KC) {
    int r = t >> 3, c = (t & 7) * 16;
    int cs = c ^ ((r >> 3) * 16);        // swizzle 16-short group by row-octet
    int row = rb + r;
    if (row < N) {
      const uint4* srcp = (const uint4*)(Hb + (size_t)row * 128 + c);
      *(uint4*)(Hl + r * 128 + cs) = srcp[0];
      *(uint4*)(Hl + r * 128 + cs + 8) = srcp[1];
    } else {
      uint4 z = make_uint4(0, 0, 0, 0);
      *(uint4*)(Hl + r * 128 + cs) = z;
      *(uint4*)(Hl + r * 128 + cs + 8) = z;
    }
    __syncthreads();
    bf16x8 a = *(const bf16x8*)(P16 + ((size_t)(rb >> 3) + quad) * 512 + (wv * 16 + l16) * 8);
#pragma unroll
    for (int ft = 0; ft < 8; ++ft) {
      bf16x8 b;
#pragma unroll
      for (int j = 0; j < 8; ++j) {
        int rr = quad * 8 + j;
        b[j] = (short)Hl[rr * 128 + ((ft ^ (rr >> 3)) * 16) + l16];
      }
      acc[ft] = __builtin_amdgcn_mfma_f32_16x16x32_bf16(a, b, acc[ft], 0, 0, 0);
    }
    __syncthreads();
  }
#pragma unroll
  for (int ft = 0; ft < 8; ++ft)
#pragma unroll
    for (int rg = 0; rg < 4; ++rg)
      unsafeAtomicAdd(&pooled[(wv * 16 + quad * 4 + rg) * DD + ft * 16 + l16], acc[ft][rg]);
}

// ---- out = pooled @ W2 + b2 ----
__global__ __launch_bounds__(128) void k_out(const float* __restrict__ pooled, const float* __restrict__ W2,
                                             const float* __restrict__ b2, float* __restrict__ out) {
  __shared__ float p[DD];
  int g = blockIdx.x, d = threadIdx.x;
  p[d] = pooled[g * DD + d];
  __syncthreads();
  float a = b2[d];
#pragma unroll 4
  for (int k = 0; k < DD; ++k) a = fmaf(p[k], W2[k * DD + d], a);
  out[g * DD + d] = a;
}

extern "C" void kernel_launch(void* const* d_in, const int* in_sizes, int n_in,
                              void* d_out, int out_size, void* d_ws, size_t ws_size,
                              hipStream_t stream) {
  const float* X  = (const float*)d_in[0];
  const float* W1 = (const float*)d_in[1];
  const float* b1 = (const float*)d_in[2];
  const float* W2 = (const float*)d_in[3];
  const float* b2 = (const float*)d_in[4];
  const int* src  = (const int*)d_in[5];
  const int* dst  = (const int*)d_in[6];
  const int* gid  = (const int*)d_in[7];
  int E = in_sizes[5];
  int N = in_sizes[7];
  int G = out_size / DD;   // 64
  int nb = (N >> 9) + 1;   // node buckets
  int Kpad = nb << 9;
  int chunk = ((Kpad + GB * KC - 1) / (GB * KC)) * KC;

  char* w = (char*)d_ws;
  size_t o = 0;
  auto carve = [&](size_t bytes) { char* p = w + o; o += (bytes + 255) & ~(size_t)255; return p; };
  // zero-init region
  int*   gcnt   = (int*)  carve((size_t)G * 4);
  float* pooled = (float*)carve((size_t)G * DD * 4);
  int*   dbin   = (int*)  carve(256 * 4);
  unsigned* tot = (unsigned*)carve(512 * 4);
  int*   dcur   = (int*)  carve(256 * 4);
  size_t zeroBytes = o;
  // rest (fully written before read)
  unsigned* rawD  = (unsigned*)carve((size_t)PB * 256 * 4);
  unsigned* rawS  = (unsigned*)carve((size_t)PB * 256 * 4);
  int*   bsD    = (int*)  carve(257 * 4);
  int*   bsS    = (int*)  carve(257 * 4);
  unsigned* curD = (unsigned*)carve(256 * 4);
  unsigned* curS = (unsigned*)carve(256 * 4);
  unsigned* pairD = (unsigned*)carve((size_t)E * 4);
  unsigned* pairS = (unsigned*)carve((size_t)E * 4);
  int*   srcS   = (int*)  carve((size_t)E * 4);
  int*   offs   = (int*)  carve((size_t)(N + 1) * 4);
  int*   degI   = (int*)  carve((size_t)N * 4);
  int*   perm   = (int*)  carve((size_t)N * 4);
  float* nsrc   = (float*)carve((size_t)N * 4);
  float* ndst   = (float*)carve((size_t)N * 4);
  uint2* pwg    = (uint2*)carve((size_t)N * 8);
  unsigned short* Wt = (unsigned short*)carve(128 * 128 * 2);
  unsigned char*  Z8 = (unsigned char*)carve((size_t)(N + 1) * DD);   // fp8, +1 zero row
  unsigned short* Hb = (unsigned short*)carve((size_t)N * DD * 2);
  unsigned short* P16 = (unsigned short*)carve((size_t)Kpad * 64 * 2);  // blocked bf16

  hipMemsetAsync(d_ws, 0, zeroBytes, stream);

  k_part1a<<<PB + 64, 256, 0, stream>>>(src, dst, gid, rawD, rawS, tot, gcnt,
                                        W1, Wt, Z8 + (size_t)N * DD, E, N, G);
  k_pscanB<<<1, 256, 0, stream>>>(tot, bsD, bsS, curD, curS);
  k_part1c<<<PB, 256, 0, stream>>>(src, dst, rawD, rawS, curD, curS, pairD, pairS, E);
  k_part2d<<<nb, 256, 0, stream>>>(pairD, bsD, gcnt, gid, offs, ndst, pwg, degI, dbin, srcS, N);
  k_dperm<<<(N + 255) / 256, 256, 0, stream>>>(degI, dbin, dcur, perm, N);
  k_pw<<<nb, 1024, 0, stream>>>(pairS, bsS, pwg, P16, nsrc, N);
  k_gemm1<<<(N + 127) / 128, 512, 0, stream>>>(X, Wt, nsrc, Z8, N);
  k_layer1<<<1024, 256, 0, stream>>>(Z8, offs, srcS, perm, b1, nsrc, ndst, Hb, N);
  k_poolgemm<<<GB, 256, 0, stream>>>(P16, Hb, pooled, N, Kpad, chunk);
  k_out<<<G, DD, 0, stream>>>(pooled, W2, b2, (float*)d_out);
}

// Round 10
// 269.595 us; speedup vs baseline: 1.0302x; 1.0236x over previous
//
#include <hip/hip_runtime.h>
#include <cstdint>

// GCN via radix partition (bucket = node>>9), packed u32 edge records.
// 8 launches: part1a -> part1c -> part2d -> pw(+dperm) -> gemm1 -> layer1
//             -> poolgemm -> out.
// pscanB deleted: consumers scan tot[512] locally; part1c claims bucket
// run-space via zero-seeded global atomic cursors.
// dperm folded into k_pw tail blocks.

#define DD 128
#define PB 512    // partition pass-1 blocks
#define GB 384    // poolgemm split-K blocks
#define KC 32     // poolgemm K-chunk
#define CHK 3200  // max edges per part1c block

typedef __attribute__((ext_vector_type(8))) short bf16x8;
typedef __attribute__((ext_vector_type(4))) float f32x4;
typedef __attribute__((ext_vector_type(2))) float f32x2;

__device__ __forceinline__ unsigned short f2bf(float f) {
  union { float f; unsigned u; } v; v.f = f;
  unsigned r = (v.u + 0x7fff + ((v.u >> 16) & 1)) >> 16;   // round-nearest-even
  return (unsigned short)r;
}
__device__ __forceinline__ unsigned cvt_pk_bf16(float lo, float hi) {
  unsigned r;
  asm("v_cvt_pk_bf16_f32 %0, %1, %2" : "=v"(r) : "v"(lo), "v"(hi));
  return r;
}
__device__ __forceinline__ unsigned char f2fp8(float f) {
  return (unsigned char)(__builtin_amdgcn_cvt_pk_fp8_f32(f, f, 0, false) & 0xff);
}

// ---- pass 1a: per-block 256-bin LDS histograms of dst>>9 and src>>9 ----
// Writes raw per-block counts AND accumulates global per-bucket totals.
// Tail blocks (blockIdx >= PB): Wt[n][k] = bf16(W1[k][n]) + Z8 zero row.
__global__ __launch_bounds__(256) void k_part1a(const int* __restrict__ src, const int* __restrict__ dst,
                                                const int* __restrict__ gid,
                                                unsigned* __restrict__ rawD, unsigned* __restrict__ rawS,
                                                unsigned* __restrict__ tot,
                                                int* __restrict__ gcnt,
                                                const float* __restrict__ W1, unsigned short* __restrict__ Wt,
                                                unsigned char* __restrict__ zrow,
                                                int E, int N, int G) {
  if (blockIdx.x >= PB) {          // wprep tail: 64 blocks x 2 rows
    int wb = blockIdx.x - PB;
    int n = wb * 2 + (threadIdx.x >> 7), k = threadIdx.x & 127;
    Wt[n * 128 + k] = f2bf(W1[k * 128 + n]);
    if (wb == 0 && threadIdx.x < 128) zrow[threadIdx.x] = 0;
    return;
  }
  __shared__ unsigned hD[256], hS[256];
  __shared__ int h64[64];
  hD[threadIdx.x] = 0; hS[threadIdx.x] = 0;
  if (threadIdx.x < 64) h64[threadIdx.x] = 0;
  __syncthreads();
  int chunk = (E + PB - 1) / PB;
  int e0 = blockIdx.x * chunk, e1 = min(E, e0 + chunk);
  for (int e = e0 + threadIdx.x; e < e1; e += 256) {
    atomicAdd(&hD[(unsigned)dst[e] >> 9], 1u);
    atomicAdd(&hS[(unsigned)src[e] >> 9], 1u);
  }
  int stride = PB * 256;
  for (int i = blockIdx.x * 256 + threadIdx.x; i < N; i += stride)
    atomicAdd(&h64[gid[i]], 1);
  __syncthreads();
  unsigned vd = hD[threadIdx.x], vs = hS[threadIdx.x];
  rawD[blockIdx.x * 256 + threadIdx.x] = vd;
  rawS[blockIdx.x * 256 + threadIdx.x] = vs;
  if (vd) atomicAdd(&tot[threadIdx.x], vd);
  if (vs) atomicAdd(&tot[256 + threadIdx.x], vs);
  if (threadIdx.x < (unsigned)G) {
    int v = h64[threadIdx.x];
    if (v) atomicAdd(&gcnt[threadIdx.x], v);
  }
}

// ---- pass 1c v5: ONE pass over (src,dst), both tables LDS-staged;
//      bucket bases from LOCAL scan of tot; run-space via zero-seeded
//      global atomic cursors (pscanB deleted).
// pairD: (dst&511)<<17 | src ; pairS: (src&511)<<17 | dst   (N < 2^17)
__global__ __launch_bounds__(256) void k_part1c(const int* __restrict__ src, const int* __restrict__ dst,
                                                const unsigned* __restrict__ rawD, const unsigned* __restrict__ rawS,
                                                const unsigned* __restrict__ tot,
                                                unsigned* __restrict__ curDg, unsigned* __restrict__ curSg,
                                                unsigned* __restrict__ pairD, unsigned* __restrict__ pairS, int E) {
  __shared__ unsigned pkD[CHK], pkS[CHK];
  __shared__ unsigned char bkD[CHK], bkS[CHK];
  __shared__ unsigned cD[256], cS[256], gbD[256], gbS[256], psc[256];
  int chunk = (E + gridDim.x - 1) / gridDim.x;
  int e0 = blockIdx.x * chunk, e1 = min(E, e0 + chunk);
  int n = e1 - e0;
  int t = threadIdx.x;
  // ---- D table ----
  unsigned vD = rawD[blockIdx.x * 256 + t];
  unsigned tD = tot[t];
  unsigned baseD = atomicAdd(&curDg[t], vD);   // bucket-RELATIVE claim
  psc[t] = tD;                                  // scan bucket totals -> bases
  __syncthreads();
  for (int off = 1; off < 256; off <<= 1) {
    unsigned x = (t >= off) ? psc[t - off] : 0;
    __syncthreads();
    psc[t] += x;
    __syncthreads();
  }
  unsigned bsDt = psc[t] - tD;                  // global base of bucket t
  __syncthreads();
  psc[t] = vD;                                  // local exclusive scan
  __syncthreads();
  for (int off = 1; off < 256; off <<= 1) {
    unsigned x = (t >= off) ? psc[t - off] : 0;
    __syncthreads();
    psc[t] += x;
    __syncthreads();
  }
  unsigned exD = psc[t] - vD;
  cD[t] = exD;
  gbD[t] = bsDt + baseD - exD;
  __syncthreads();
  // ---- S table ----
  unsigned vS = rawS[blockIdx.x * 256 + t];
  unsigned tS = tot[256 + t];
  unsigned baseS = atomicAdd(&curSg[t], vS);
  psc[t] = tS;
  __syncthreads();
  for (int off = 1; off < 256; off <<= 1) {
    unsigned x = (t >= off) ? psc[t - off] : 0;
    __syncthreads();
    psc[t] += x;
    __syncthreads();
  }
  unsigned bsSt = psc[t] - tS;
  __syncthreads();
  psc[t] = vS;
  __syncthreads();
  for (int off = 1; off < 256; off <<= 1) {
    unsigned x = (t >= off) ? psc[t - off] : 0;
    __syncthreads();
    psc[t] += x;
    __syncthreads();
  }
  unsigned exS = psc[t] - vS;
  cS[t] = exS;
  gbS[t] = bsSt + baseS - exS;
  __syncthreads();
  // ---- placement ----
  for (int i = t; i < n; i += 256) {
    unsigned sv = (unsigned)src[e0 + i], dv = (unsigned)dst[e0 + i];
    unsigned bD = dv >> 9, bS = sv >> 9;
    unsigned pD = atomicAdd(&cD[bD], 1u);
    pkD[pD] = ((dv & 511u) << 17) | sv;
    bkD[pD] = (unsigned char)bD;
    unsigned pS = atomicAdd(&cS[bS], 1u);
    pkS[pS] = ((sv & 511u) << 17) | dv;
    bkS[pS] = (unsigned char)bS;
  }
  __syncthreads();
  for (int i = t; i < n; i += 256)
    pairD[gbD[bkD[i]] + i] = pkD[i];
  for (int i = t; i < n; i += 256)
    pairS[gbS[bkS[i]] + i] = pkS[i];
}

// ---- pass 2d (+norm fused +degree hist): per dst-bucket; bucket bounds
//      from LOCAL scan of tot[0..255] ----
__global__ __launch_bounds__(256) void k_part2d(const unsigned* __restrict__ pairD,
                                                const unsigned* __restrict__ tot,
                                                const int* __restrict__ gcnt, const int* __restrict__ gid,
                                                int* __restrict__ offs, float* __restrict__ ndst,
                                                uint2* __restrict__ pwg, int* __restrict__ degI,
                                                int* __restrict__ dbin,
                                                int* __restrict__ srcS, int N) {
  __shared__ unsigned hist[512], excl[512], psc[256];
  __shared__ int sInc[256], ldb[256];
  int k = blockIdx.x, base = k << 9;
  int t = threadIdx.x;
  sInc[t] = (int)tot[t];
  hist[t] = 0; hist[t + 256] = 0;
  ldb[t] = 0;
  __syncthreads();
  for (int off = 1; off < 256; off <<= 1) {
    int x = (t >= off) ? sInc[t - off] : 0;
    __syncthreads();
    sInc[t] += x;
    __syncthreads();
  }
  int b0 = k ? sInc[k - 1] : 0;
  int b1 = sInc[k];
  for (int i = b0 + t; i < b1; i += 256)
    atomicAdd(&hist[pairD[i] >> 17], 1u);
  __syncthreads();
  unsigned s0 = hist[2 * t], s1 = hist[2 * t + 1];
  unsigned pr = s0 + s1;
  psc[t] = pr;
  __syncthreads();
  for (int off = 1; off < 256; off <<= 1) {
    unsigned x = (t >= off) ? psc[t - off] : 0;
    __syncthreads();
    psc[t] += x;
    __syncthreads();
  }
  unsigned pex = psc[t] - pr;
  excl[2 * t] = pex;
  excl[2 * t + 1] = pex + s0;
  __syncthreads();
  for (int j = t; j < 512; j += 256) {
    int node = base + j;
    if (node <= N) offs[node] = b0 + (int)excl[j];
    if (node < N) {
      int dg = (int)hist[j];
      degI[node] = dg;
      atomicAdd(&ldb[255 - min(dg, 255)], 1);   // reversed bin -> descending sort
      float gi = (float)dg; gi = gi > 0.f ? gi : 1.f;
      float nd = rsqrtf(gi);
      ndst[node] = nd;
      float c = (float)gcnt[gid[node]]; c = c > 1.f ? c : 1.f;
      float w = nd / c;
      union { float f; unsigned u; } v; v.f = w;
      pwg[node] = make_uint2(v.u, (unsigned)gid[node]);
    }
  }
  __syncthreads();
  if (ldb[t]) atomicAdd(&dbin[t], ldb[t]);
  for (int i = b0 + t; i < b1; i += 256) {
    unsigned pkv = pairD[i];
    unsigned pos = atomicAdd(&excl[pkv >> 17], 1u);
    srcS[b0 + (int)pos] = (int)(pkv & 0x1FFFFu);
  }
}

// ---- k_pw (+dperm tail): blocks < nbk do per-src-bucket P-tile + nsrc
//      (bucket bounds from local scan of tot[256..511]);
//      blocks >= nbk do the degree counting-sort scatter (perm).
__global__ __launch_bounds__(1024, 1) void k_pw(const unsigned* __restrict__ pairS,
                                                const unsigned* __restrict__ tot,
                                                const uint2* __restrict__ pwg,
                                                unsigned short* __restrict__ P16,
                                                float* __restrict__ nsrc,
                                                const int* __restrict__ degI, const int* __restrict__ dbin,
                                                int* __restrict__ dcur, int* __restrict__ perm,
                                                int N, int nbk) {
  __shared__ float tile[512 * 64];   // 128 KB
  __shared__ unsigned hist[512];     // 2 KB
  __shared__ int s2[256], lh[256], lcur[256];
  int t = threadIdx.x;
  if (blockIdx.x >= nbk) {           // ---- dperm tail blocks ----
    int v2 = 0;
    if (t < 256) { s2[t] = dbin[t]; v2 = s2[t]; lh[t] = 0; }
    __syncthreads();
    for (int off = 1; off < 256; off <<= 1) {
      int x = (t < 256 && t >= off) ? s2[t - off] : 0;
      __syncthreads();
      if (t < 256) s2[t] += x;
      __syncthreads();
    }
    int i = (blockIdx.x - nbk) * 1024 + t;
    int bin = 0;
    if (i < N) {
      bin = 255 - min(degI[i], 255);
      atomicAdd(&lh[bin], 1);
    }
    __syncthreads();
    if (t < 256) {
      int r = lh[t] ? atomicAdd(&dcur[t], lh[t]) : 0;
      lcur[t] = (s2[t] - v2) + r;
    }
    __syncthreads();
    if (i < N) {
      int pos = atomicAdd(&lcur[bin], 1);
      perm[pos] = i;
    }
    return;
  }
  int k = blockIdx.x, base = k << 9;
  if (t < 256) s2[t] = (int)tot[256 + t];
  __syncthreads();
  for (int off = 1; off < 256; off <<= 1) {
    int x = (t < 256 && t >= off) ? s2[t - off] : 0;
    __syncthreads();
    if (t < 256) s2[t] += x;
    __syncthreads();
  }
  int b0 = k ? s2[k - 1] : 0;
  int b1 = s2[k];
  for (int i = t; i < 512 * 64; i += 1024) tile[i] = 0.f;
  if (t < 512) hist[t] = 0;
  __syncthreads();
  for (int i = b0 + t; i < b1; i += 1024) {
    unsigned pkv = pairS[i];
    unsigned dv = pkv & 0x1FFFFu;
    unsigned sloc = pkv >> 17;
    atomicAdd(&hist[sloc], 1u);
    uint2 u = pwg[dv];
    union { unsigned u; float f; } w; w.u = u.x;
    atomicAdd(&tile[sloc * 64 + u.y], w.f);
  }
  __syncthreads();
  if (t < 512) {
    int node = base + t;
    if (node < N) {
      float g = (float)hist[t]; g = g > 0.f ? g : 1.f;
      nsrc[node] = rsqrtf(g);
    }
  }
  for (int grp = t; grp < 4096; grp += 1024) {
    int qb = grp >> 6, g = grp & 63;
    unsigned w0 = cvt_pk_bf16(tile[(qb * 8 + 0) * 64 + g], tile[(qb * 8 + 1) * 64 + g]);
    unsigned w1 = cvt_pk_bf16(tile[(qb * 8 + 2) * 64 + g], tile[(qb * 8 + 3) * 64 + g]);
    unsigned w2 = cvt_pk_bf16(tile[(qb * 8 + 4) * 64 + g], tile[(qb * 8 + 5) * 64 + g]);
    unsigned w3 = cvt_pk_bf16(tile[(qb * 8 + 6) * 64 + g], tile[(qb * 8 + 7) * 64 + g]);
    uint4 o = make_uint4(w0, w1, w2, w3);
    *(uint4*)(P16 + ((size_t)(base >> 3) + qb) * 512 + g * 8) = o;
  }
}

// ---- GEMM1 v3 (MFMA): Z8 = fp8( (X @ W1) * nsrc[row] ) ----
// 128 rows/block (512 thr, 8 waves): Wt LDS stage amortized, X loads +
// nsrc hoisted before the MFMA loop.
__global__ __launch_bounds__(512) void k_gemm1(const float* __restrict__ X, const unsigned short* __restrict__ Wt,
                                               const float* __restrict__ nsrc,
                                               unsigned char* __restrict__ Z8, int N) {
  __shared__ unsigned short Wl[128 * 128];   // 32 KB
  int wave = threadIdx.x >> 6, lane = threadIdx.x & 63;
  int quad = lane >> 4, l16 = lane & 15;
  int row0 = blockIdx.x * 128 + wave * 16;
  int arow = row0 + l16; if (arow >= N) arow = N - 1;
  const float* xr = X + (size_t)arow * 128 + quad * 8;
  float4 xv[8];
#pragma unroll
  for (int kbi = 0; kbi < 4; ++kbi) {
    xv[2 * kbi]     = *(const float4*)(xr + kbi * 32);
    xv[2 * kbi + 1] = *(const float4*)(xr + kbi * 32 + 4);
  }
  int rbase = row0 + quad * 4;
  float sc[4];
#pragma unroll
  for (int r = 0; r < 4; ++r) {
    int row = rbase + r; if (row >= N) row = N - 1;
    sc[r] = nsrc[row];
  }
  for (int i = threadIdx.x; i < 2048; i += 512) {
    int wrow = i >> 4, sgrp = i & 15;
    *(uint4*)(Wl + wrow * 128 + ((sgrp ^ (wrow & 15)) << 3)) = ((const uint4*)Wt)[i];
  }
  __syncthreads();
  f32x4 acc[8];
#pragma unroll
  for (int i = 0; i < 8; ++i) acc[i] = (f32x4){0.f, 0.f, 0.f, 0.f};
#pragma unroll
  for (int kbi = 0; kbi < 4; ++kbi) {
    float4 x0 = xv[2 * kbi], x1 = xv[2 * kbi + 1];
    union { unsigned u[4]; bf16x8 v; } A;
    A.u[0] = cvt_pk_bf16(x0.x, x0.y);
    A.u[1] = cvt_pk_bf16(x0.z, x0.w);
    A.u[2] = cvt_pk_bf16(x1.x, x1.y);
    A.u[3] = cvt_pk_bf16(x1.z, x1.w);
#pragma unroll
    for (int nt = 0; nt < 8; ++nt) {
      bf16x8 b = *(const bf16x8*)(Wl + (nt * 16 + l16) * 128 + (((kbi * 4 + quad) ^ l16) << 3));
      acc[nt] = __builtin_amdgcn_mfma_f32_16x16x32_bf16(A.v, b, acc[nt], 0, 0, 0);
    }
  }
#pragma unroll
  for (int r = 0; r < 4; ++r) {
    int row = rbase + r;
    if (row < N) {
      float s = sc[r];
#pragma unroll
      for (int nt = 0; nt < 8; ++nt)
        Z8[(size_t)row * 128 + nt * 16 + l16] = f2fp8(acc[nt][r] * s);
    }
  }
}

// ---- layer1 v7: persistent grid-stride; octet owns a dst (8 dsts/wave) ----
#define ACC16(u) do {                                             \
    c0 += __builtin_amdgcn_cvt_pk_f32_fp8((u).x, false);          \
    c1 += __builtin_amdgcn_cvt_pk_f32_fp8((u).x, true);           \
    c2 += __builtin_amdgcn_cvt_pk_f32_fp8((u).y, false);          \
    c3 += __builtin_amdgcn_cvt_pk_f32_fp8((u).y, true);           \
    c4 += __builtin_amdgcn_cvt_pk_f32_fp8((u).z, false);          \
    c5 += __builtin_amdgcn_cvt_pk_f32_fp8((u).z, true);           \
    c6 += __builtin_amdgcn_cvt_pk_f32_fp8((u).w, false);          \
    c7 += __builtin_amdgcn_cvt_pk_f32_fp8((u).w, true);           \
  } while (0)

__global__ __launch_bounds__(256) void k_layer1(const unsigned char* __restrict__ Z8,
                                                const int* __restrict__ offs, const int* __restrict__ srcS,
                                                const int* __restrict__ perm,
                                                const float* __restrict__ b1,
                                                const float* __restrict__ nsrc, const float* __restrict__ ndst,
                                                unsigned short* __restrict__ Hb, int N) {
  int lane = threadIdx.x & 63;
  int oct = lane >> 3, l8 = lane & 7;
  const int f = l8 * 16;                 // 16 channels per lane
  const unsigned char* zb = Z8 + f;
  int gstride = gridDim.x * 32;
  for (int base = blockIdx.x * 32; base < N; base += gstride) {
    int dd = base + (threadIdx.x >> 6) * 8 + oct;
    bool live = dd < N;
    int pd = perm[live ? dd : 0];
    int start = offs[pd];
    int end = live ? offs[pd + 1] : start;
    float nd = ndst[pd], ns = nsrc[pd];
    f32x2 c0 = {0.f, 0.f}, c1 = {0.f, 0.f}, c2 = {0.f, 0.f}, c3 = {0.f, 0.f};
    f32x2 c4 = {0.f, 0.f}, c5 = {0.f, 0.f}, c6 = {0.f, 0.f}, c7 = {0.f, 0.f};
    int e = start;
    int rem = end - start;
    int s0 = N, s1 = N, s2 = N, s3 = N;
    if (rem > 0) s0 = srcS[e];
    if (rem > 1) s1 = srcS[e + 1];
    if (rem > 2) s2 = srcS[e + 2];
    if (rem > 3) s3 = srcS[e + 3];
    while (__any(rem > 0)) {
      uint4 u0 = *(const uint4*)(zb + ((size_t)s0 << 7));
      uint4 u1 = *(const uint4*)(zb + ((size_t)s1 << 7));
      uint4 u2 = *(const uint4*)(zb + ((size_t)s2 << 7));
      uint4 u3 = *(const uint4*)(zb + ((size_t)s3 << 7));
      int n0 = N, n1 = N, n2 = N, n3 = N;
      if (rem > 4) n0 = srcS[e + 4];      // prefetch next 4 before consuming
      if (rem > 5) n1 = srcS[e + 5];
      if (rem > 6) n2 = srcS[e + 6];
      if (rem > 7) n3 = srcS[e + 7];
      ACC16(u0);
      ACC16(u1);
      ACC16(u2);
      ACC16(u3);
      s0 = n0; s1 = n1; s2 = n2; s3 = n3;
      e += 4;
      rem -= 4;
    }
    if (live) {
      float4 bv0 = *(const float4*)(b1 + f);
      float4 bv1 = *(const float4*)(b1 + f + 4);
      float4 bv2 = *(const float4*)(b1 + f + 8);
      float4 bv3 = *(const float4*)(b1 + f + 12);
      float h0 = fmaxf(fmaf(nd, c0[0], bv0.x), 0.f) * ns;
      float h1 = fmaxf(fmaf(nd, c0[1], bv0.y), 0.f) * ns;
      float h2 = fmaxf(fmaf(nd, c1[0], bv0.z), 0.f) * ns;
      float h3 = fmaxf(fmaf(nd, c1[1], bv0.w), 0.f) * ns;
      float h4 = fmaxf(fmaf(nd, c2[0], bv1.x), 0.f) * ns;
      float h5 = fmaxf(fmaf(nd, c2[1], bv1.y), 0.f) * ns;
      float h6 = fmaxf(fmaf(nd, c3[0], bv1.z), 0.f) * ns;
      float h7 = fmaxf(fmaf(nd, c3[1], bv1.w), 0.f) * ns;
      float h8 = fmaxf(fmaf(nd, c4[0], bv2.x), 0.f) * ns;
      float h9 = fmaxf(fmaf(nd, c4[1], bv2.y), 0.f) * ns;
      float hA = fmaxf(fmaf(nd, c5[0], bv2.z), 0.f) * ns;
      float hB = fmaxf(fmaf(nd, c5[1], bv2.w), 0.f) * ns;
      float hC = fmaxf(fmaf(nd, c6[0], bv3.x), 0.f) * ns;
      float hD = fmaxf(fmaf(nd, c6[1], bv3.y), 0.f) * ns;
      float hE = fmaxf(fmaf(nd, c7[0], bv3.z), 0.f) * ns;
      float hF = fmaxf(fmaf(nd, c7[1], bv3.w), 0.f) * ns;
      unsigned short* hrow = Hb + (size_t)pd * 128 + f;
      *(uint4*)hrow = make_uint4(cvt_pk_bf16(h0, h1), cvt_pk_bf16(h2, h3),
                                 cvt_pk_bf16(h4, h5), cvt_pk_bf16(h6, h7));
      *(uint4*)(hrow + 8) = make_uint4(cvt_pk_bf16(h8, h9), cvt_pk_bf16(hA, hB),
                                       cvt_pk_bf16(hC, hD), cvt_pk_bf16(hE, hF));
    }
  }
}

// ---- k_poolgemm (MFMA): pooled += P_blk^T · H  (split-K, bf16, f32 acc) ----
__global__ __launch_bounds__(256) void k_poolgemm(const unsigned short* __restrict__ P16,
                                                  const unsigned short* __restrict__ Hb,
                                                  float* __restrict__ pooled, int N, int Kpad, int chunk) {
  __shared__ unsigned short Hl[KC * 128];   // 8 KB, 16-short groups XOR-swizzled by (row>>3)
  int t = threadIdx.x;
  int r0 = blockIdx.x * chunk;
  int r1 = min(Kpad, r0 + chunk);
  int wv = t >> 6, lane = t & 63, quad = lane >> 4, l16 = lane & 15;
  f32x4 acc[8];
#pragma unroll
  for (int i = 0; i < 8; ++i) acc[i] = (f32x4){0.f, 0.f, 0.f, 0.f};
  for (int rb = r0; rb < r1; rb += KC) {
    int r = t >> 3, c = (t & 7) * 16;
    int cs = c ^ ((r >> 3) * 16);        // swizzle 16-short group by row-octet
    int row = rb + r;
    if (row < N) {
      const uint4* srcp = (const uint4*)(Hb + (size_t)row * 128 + c);
      *(uint4*)(Hl + r * 128 + cs) = srcp[0];
      *(uint4*)(Hl + r * 128 + cs + 8) = srcp[1];
    } else {
      uint4 z = make_uint4(0, 0, 0, 0);
      *(uint4*)(Hl + r * 128 + cs) = z;
      *(uint4*)(Hl + r * 128 + cs + 8) = z;
    }
    __syncthreads();
    bf16x8 a = *(const bf16x8*)(P16 + ((size_t)(rb >> 3) + quad) * 512 + (wv * 16 + l16) * 8);
#pragma unroll
    for (int ft = 0; ft < 8; ++ft) {
      bf16x8 b;
#pragma unroll
      for (int j = 0; j < 8; ++j) {
        int rr = quad * 8 + j;
        b[j] = (short)Hl[rr * 128 + ((ft ^ (rr >> 3)) * 16) + l16];
      }
      acc[ft] = __builtin_amdgcn_mfma_f32_16x16x32_bf16(a, b, acc[ft], 0, 0, 0);
    }
    __syncthreads();
  }
#pragma unroll
  for (int ft = 0; ft < 8; ++ft)
#pragma unroll
    for (int rg = 0; rg < 4; ++rg)
      unsafeAtomicAdd(&pooled[(wv * 16 + quad * 4 + rg) * DD + ft * 16 + l16], acc[ft][rg]);
}

// ---- out = pooled @ W2 + b2 ----
__global__ __launch_bounds__(128) void k_out(const float* __restrict__ pooled, const float* __restrict__ W2,
                                             const float* __restrict__ b2, float* __restrict__ out) {
  __shared__ float p[DD];
  int g = blockIdx.x, d = threadIdx.x;
  p[d] = pooled[g * DD + d];
  __syncthreads();
  float a = b2[d];
#pragma unroll 4
  for (int k = 0; k < DD; ++k) a = fmaf(p[k], W2[k * DD + d], a);
  out[g * DD + d] = a;
}

extern "C" void kernel_launch(void* const* d_in, const int* in_sizes, int n_in,
                              void* d_out, int out_size, void* d_ws, size_t ws_size,
                              hipStream_t stream) {
  const float* X  = (const float*)d_in[0];
  const float* W1 = (const float*)d_in[1];
  const float* b1 = (const float*)d_in[2];
  const float* W2 = (const float*)d_in[3];
  const float* b2 = (const float*)d_in[4];
  const int* src  = (const int*)d_in[5];
  const int* dst  = (const int*)d_in[6];
  const int* gid  = (const int*)d_in[7];
  int E = in_sizes[5];
  int N = in_sizes[7];
  int G = out_size / DD;   // 64
  int nb = (N >> 9) + 1;   // node buckets
  int Kpad = nb << 9;
  int chunk = ((Kpad + GB * KC - 1) / (GB * KC)) * KC;
  int ndb = (N + 1023) / 1024;   // dperm tail blocks in k_pw

  char* w = (char*)d_ws;
  size_t o = 0;
  auto carve = [&](size_t bytes) { char* p = w + o; o += (bytes + 255) & ~(size_t)255; return p; };
  // zero-init region
  int*   gcnt   = (int*)  carve((size_t)G * 4);
  float* pooled = (float*)carve((size_t)G * DD * 4);
  int*   dbin   = (int*)  carve(256 * 4);
  unsigned* tot = (unsigned*)carve(512 * 4);
  int*   dcur   = (int*)  carve(256 * 4);
  unsigned* curD = (unsigned*)carve(256 * 4);
  unsigned* curS = (unsigned*)carve(256 * 4);
  size_t zeroBytes = o;
  // rest (fully written before read)
  unsigned* rawD  = (unsigned*)carve((size_t)PB * 256 * 4);
  unsigned* rawS  = (unsigned*)carve((size_t)PB * 256 * 4);
  unsigned* pairD = (unsigned*)carve((size_t)E * 4);
  unsigned* pairS = (unsigned*)carve((size_t)E * 4);
  int*   srcS   = (int*)  carve((size_t)E * 4);
  int*   offs   = (int*)  carve((size_t)(N + 1) * 4);
  int*   degI   = (int*)  carve((size_t)N * 4);
  int*   perm   = (int*)  carve((size_t)N * 4);
  float* nsrc   = (float*)carve((size_t)N * 4);
  float* ndst   = (float*)carve((size_t)N * 4);
  uint2* pwg    = (uint2*)carve((size_t)N * 8);
  unsigned short* Wt = (unsigned short*)carve(128 * 128 * 2);
  unsigned char*  Z8 = (unsigned char*)carve((size_t)(N + 1) * DD);   // fp8, +1 zero row
  unsigned short* Hb = (unsigned short*)carve((size_t)N * DD * 2);
  unsigned short* P16 = (unsigned short*)carve((size_t)Kpad * 64 * 2);  // blocked bf16

  hipMemsetAsync(d_ws, 0, zeroBytes, stream);

  k_part1a<<<PB + 64, 256, 0, stream>>>(src, dst, gid, rawD, rawS, tot, gcnt,
                                        W1, Wt, Z8 + (size_t)N * DD, E, N, G);
  k_part1c<<<PB, 256, 0, stream>>>(src, dst, rawD, rawS, tot, curD, curS, pairD, pairS, E);
  k_part2d<<<nb, 256, 0, stream>>>(pairD, tot, gcnt, gid, offs, ndst, pwg, degI, dbin, srcS, N);
  k_pw<<<nb + ndb, 1024, 0, stream>>>(pairS, tot, pwg, P16, nsrc, degI, dbin, dcur, perm, N, nb);
  k_gemm1<<<(N + 127) / 128, 512, 0, stream>>>(X, Wt, nsrc, Z8, N);
  k_layer1<<<1024, 256, 0, stream>>>(Z8, offs, srcS, perm, b1, nsrc, ndst, Hb, N);
  k_poolgemm<<<GB, 256, 0, stream>>>(P16, Hb, pooled, N, Kpad, chunk);
  k_out<<<G, DD, 0, stream>>>(pooled, W2, b2, (float*)d_out);
}